// Round 23
// baseline (57.898 us; speedup 1.0000x reference)
//
#include <hip/hip_runtime.h>

// VanillaGNN via MFMA: B=262144 graphs, N=8 nodes, DIN=3, DH=32, DOUT=1.
// Round-20 base (32.3us) + layer-1 moved fully to MFMA via fold reorder
// h1 = relu(A@(x@W1) + b1), FIXED operand order (r22 bug: contraction-dim
// mismatch — L0 with W1 as A-operand gives regs=hidden, but AGG contracts
// over nodes. Fix: x as A-operand, W1 as B-operand -> L0 out lane=hidden,
// regs=node -> AGG1 contracts nodes -> out lane=node, regs=hidden = the
// verified old L1 layout; downstream chain untouched).
//   L0:  P0 = x@W1: A[row=node][k]=xhi(q=0)/xlo(q=1), B=W1hi then W1lo
//        (both halves) -> (xhi+xlo)(W1hi+W1lo) exact. C=zerov.
//   AGG1: direct pi-cvt of P0 (regs=node) @ a32hi, C=b1rv, then relu.
//   GEMM1/AGG2/epilogue unchanged from r20/21.
// PRE-COMMIT: absmax > 4.5e-4 -> revert to r20 VALU y-stage.
// CANARIES: LDS 11776 (+8KB = spill), FETCH ~12.3MB.
// Verified layouts (gfx950 mfma_f32_32x32x16_bf16, rounds 3-21):
//   A: lane row=l&31, k=8*(l>>5)+j   B: col=l&31, same k
//   C/D: col=l&31, row=(reg&3)+8*(reg>>2)+4*(l>>5)
// pi(kk,q) = (kk&3)+8*(kk>>2)+4q.
// Precision ledger (measured-free): tlo, w2lo, a32lo, plo. New: t0 bf16 rnd.
// Occupancy verdict (r13-r19): pinned at 2 waves/SIMD; registers are free.

typedef __bf16 bf16x8 __attribute__((ext_vector_type(8)));
typedef float  f32x16 __attribute__((ext_vector_type(16)));

#define GPT 32  // graphs per block tile (4 waves x 2 pipelines x 4 graphs)

__global__ __launch_bounds__(256, 2) void gnn_kernel(
    const float* __restrict__ x,       // [B,8,3]
    const int* __restrict__ ei,        // [2,32] int32
    const float* __restrict__ W1,      // [3,32]
    const float* __restrict__ b1,      // [32]
    const float* __restrict__ W2,      // [32,32]
    const float* __restrict__ b2,      // [32]
    const float* __restrict__ Wout,    // [32]
    const float* __restrict__ bout,    // [1]
    float* __restrict__ out,           // [B]
    int B, int ntiles)
{
    __shared__ float As[64];           // A[n][m] (n=dst)
    __shared__ float degs[8], dinvs[8];
    __shared__ float W1s[96], b1s[32], W2s[1024], b2s[32], Wouts[32];
    __shared__ float xs[2][GPT * 24];  // double-buffered [g][8][3]

    const int tid = threadIdx.x;

    // ---- stage weights / build A (once per block) ----
    if (tid < 96) W1s[tid] = W1[tid];
    if (tid < 64) As[tid] = 0.0f;
    if (tid < 32) { b1s[tid] = b1[tid]; b2s[tid] = b2[tid]; Wouts[tid] = Wout[tid]; }
    if (tid < 8)  degs[tid] = 1.0f;
    for (int i = tid; i < 1024; i += 256) W2s[i] = W2[i];
    __syncthreads();
    if (tid < 32) { int d = ei[32 + tid]; atomicAdd(&degs[d], 1.0f); }
    __syncthreads();
    if (tid < 8) dinvs[tid] = 1.0f / sqrtf(degs[tid]);
    __syncthreads();
    if (tid < 32) {
        int s = ei[tid], d = ei[32 + tid];
        atomicAdd(&As[d * 8 + s], dinvs[s] * dinvs[d]);
    } else if (tid < 40) {
        int n = tid - 32;
        atomicAdd(&As[n * 8 + n], dinvs[n] * dinvs[n]);
    }
    __syncthreads();

    // ---- per-lane constants ----
    const int lane = tid & 63;
    const int wv   = tid >> 6;    // wave 0..3
    const int r    = lane & 31;
    const int q    = lane >> 5;   // k-half selector
    const int n8   = r & 7;       // node within graph
    const int gl   = r >> 3;      // graph within pipeline
    const int g0   = wv * 4 + gl;       // pipeline-0 graph
    const int g1   = 16 + wv * 4 + gl;  // pipeline-1 graph

    float arow[8];
    #pragma unroll
    for (int m = 0; m < 8; m++) arow[m] = As[n8 * 8 + m];

    // W1 B-frags (hidden col = r): slots 0-2 = W1[j][r], hi/lo split;
    // same values in both q halves (pairs with xA's q-dependent hi/lo)
    bf16x8 w1Bhi, w1Blo;
    #pragma unroll
    for (int j = 0; j < 8; j++) { w1Bhi[j] = (__bf16)0.0f; w1Blo[j] = (__bf16)0.0f; }
    #pragma unroll
    for (int j = 0; j < 3; j++) {
        float v = W1s[j * 32 + r];
        __bf16 h = (__bf16)v;
        w1Bhi[j] = h; w1Blo[j] = (__bf16)(v - (float)h);
    }

    // W2 B-frags in pi-order (hi only)
    bf16x8 w2hi[2];
    #pragma unroll
    for (int s = 0; s < 2; s++) {
        #pragma unroll
        for (int j = 0; j < 8; j++) {
            int kk = 8 * s + j;
            int hid = (kk & 3) + 8 * (kk >> 2) + 4 * q;
            w2hi[s][j] = (__bf16)W2s[hid * 32 + r];
        }
    }
    // A32T B-frags in pi-order (hi only)
    bf16x8 a32hi[2];
    #pragma unroll
    for (int s = 0; s < 2; s++) {
        #pragma unroll
        for (int j = 0; j < 8; j++) {
            int kk = 8 * s + j;
            float v = ((kk >> 2) == gl) ? arow[(kk & 3) + 4 * q] : 0.0f;
            a32hi[s][j] = (__bf16)v;
        }
    }
    // persistent C-operand vectors (pi-order over hidden) + epilogue wout
    f32x16 zerov, b1rv, b2rv;
    float woutr[16];
    #pragma unroll
    for (int k = 0; k < 16; k++) {
        int hk = (k & 3) + 8 * (k >> 2) + 4 * q;
        zerov[k] = 0.0f;
        b1rv[k] = b1s[hk];
        b2rv[k] = b2s[hk];
        woutr[k] = Wouts[hk];
    }
    const float boutv = bout[0];

    // ---- x prefetch (tile 0) ----
    const float4* x4 = reinterpret_cast<const float4*>(x);
    float4 nxt;
    if (tid < 192 && blockIdx.x < ntiles)
        nxt = x4[(long long)blockIdx.x * 192 + tid];
    int buf = 0;

    // ---- tile loop: 1 barrier per 2 pipelines; prefetch after barrier ----
    for (int tile = blockIdx.x; tile < ntiles; tile += gridDim.x) {
        const long long gbase = (long long)tile * GPT;
        if (tid < 192) *reinterpret_cast<float4*>(&xs[buf][tid * 4]) = nxt;
        __syncthreads();
        int tnext = tile + gridDim.x;
        if (tid < 192 && tnext < ntiles)
            nxt = x4[(long long)tnext * 192 + tid];   // in flight during compute

        // ---- per-lane x read: own node's 3 floats (broadcast across q) ----
        const float* xp0 = &xs[buf][g0 * 24 + n8 * 3];
        const float* xp1 = &xs[buf][g1 * 24 + n8 * 3];
        float x00 = xp0[0], x01 = xp0[1], x02 = xp0[2];
        float x10 = xp1[0], x11 = xp1[1], x12 = xp1[2];

        // ---- xA A-frags (q=0 half: hi, q=1 half: lo; slots 3..7 = 0) ----
        bf16x8 xA0, xA1;
        #pragma unroll
        for (int j = 0; j < 8; j++) { xA0[j] = (__bf16)0.0f; xA1[j] = (__bf16)0.0f; }
        {
            __bf16 h0 = (__bf16)x00, h1 = (__bf16)x01, h2 = (__bf16)x02;
            xA0[0] = q ? (__bf16)(x00 - (float)h0) : h0;
            xA0[1] = q ? (__bf16)(x01 - (float)h1) : h1;
            xA0[2] = q ? (__bf16)(x02 - (float)h2) : h2;
            __bf16 g0h = (__bf16)x10, g1h = (__bf16)x11, g2h = (__bf16)x12;
            xA1[0] = q ? (__bf16)(x10 - (float)g0h) : g0h;
            xA1[1] = q ? (__bf16)(x11 - (float)g1h) : g1h;
            xA1[2] = q ? (__bf16)(x12 - (float)g2h) : g2h;
        }

        // ---- L0: P0 = x@W1 — A = xA (node rows), B = W1hi then W1lo ----
        // out: lane=hidden, regs=node (contract-over-node ready for AGG1)
        f32x16 vacc0, vacc1;
        vacc0 = __builtin_amdgcn_mfma_f32_32x32x16_bf16(xA0, w1Bhi, zerov, 0, 0, 0);
        vacc1 = __builtin_amdgcn_mfma_f32_32x32x16_bf16(xA1, w1Bhi, zerov, 0, 0, 0);
        vacc0 = __builtin_amdgcn_mfma_f32_32x32x16_bf16(xA0, w1Blo, vacc0, 0, 0, 0);
        vacc1 = __builtin_amdgcn_mfma_f32_32x32x16_bf16(xA1, w1Blo, vacc1, 0, 0, 0);

        // ---- t0 A-frags: hi-only DIRECT conversion (regs=node = contraction) ----
        bf16x8 t0hi0[2], t0hi1[2];
        #pragma unroll
        for (int s = 0; s < 2; s++) {
            #pragma unroll
            for (int j = 0; j < 8; j++) {
                t0hi0[s][j] = (__bf16)vacc0[8 * s + j];
                t0hi1[s][j] = (__bf16)vacc1[8 * s + j];
            }
        }

        // ---- AGG1: A-apply; C = b1rv (bias after aggregation) ----
        // out: lane=node, regs=hidden — identical to old L1 output layout
        vacc0 = __builtin_amdgcn_mfma_f32_32x32x16_bf16(t0hi0[0], a32hi[0], b1rv, 0, 0, 0);
        vacc1 = __builtin_amdgcn_mfma_f32_32x32x16_bf16(t0hi1[0], a32hi[0], b1rv, 0, 0, 0);
        vacc0 = __builtin_amdgcn_mfma_f32_32x32x16_bf16(t0hi0[1], a32hi[1], vacc0, 0, 0, 0);
        vacc1 = __builtin_amdgcn_mfma_f32_32x32x16_bf16(t0hi1[1], a32hi[1], vacc1, 0, 0, 0);

        // ---- relu -> h1, hi-only A-frags ----
        bf16x8 phi0[2], phi1[2];
        #pragma unroll
        for (int s = 0; s < 2; s++) {
            #pragma unroll
            for (int j = 0; j < 8; j++) {
                phi0[s][j] = (__bf16)fmaxf(vacc0[8 * s + j], 0.0f);
                phi1[s][j] = (__bf16)fmaxf(vacc1[8 * s + j], 0.0f);
            }
        }

        // ---- GEMM1 MFMAs, interleaved; C = zerov ----
        vacc0 = __builtin_amdgcn_mfma_f32_32x32x16_bf16(phi0[0], w2hi[0], zerov, 0, 0, 0);
        vacc1 = __builtin_amdgcn_mfma_f32_32x32x16_bf16(phi1[0], w2hi[0], zerov, 0, 0, 0);
        vacc0 = __builtin_amdgcn_mfma_f32_32x32x16_bf16(phi0[1], w2hi[1], vacc0, 0, 0, 0);
        vacc1 = __builtin_amdgcn_mfma_f32_32x32x16_bf16(phi1[1], w2hi[1], vacc1, 0, 0, 0);

        // ---- t^T A-frags: hi-only DIRECT conversion ----
        bf16x8 thi0[2], thi1[2];
        #pragma unroll
        for (int s = 0; s < 2; s++) {
            #pragma unroll
            for (int j = 0; j < 8; j++) {
                thi0[s][j] = (__bf16)vacc0[8 * s + j];
                thi1[s][j] = (__bf16)vacc1[8 * s + j];
            }
        }

        // ---- AGG2 MFMAs, interleaved; C = b2rv ----
        vacc0 = __builtin_amdgcn_mfma_f32_32x32x16_bf16(thi0[0], a32hi[0], b2rv, 0, 0, 0);
        vacc1 = __builtin_amdgcn_mfma_f32_32x32x16_bf16(thi1[0], a32hi[0], b2rv, 0, 0, 0);
        vacc0 = __builtin_amdgcn_mfma_f32_32x32x16_bf16(thi0[1], a32hi[1], vacc0, 0, 0, 0);
        vacc1 = __builtin_amdgcn_mfma_f32_32x32x16_bf16(thi1[1], a32hi[1], vacc1, 0, 0, 0);

        // ---- epilogues, interleaved (independent shfl chains) ----
        float ss0 = 0.0f, ss1 = 0.0f;
        #pragma unroll
        for (int k = 0; k < 16; k++) {
            ss0 = fmaf(fmaxf(vacc0[k], 0.0f), woutr[k], ss0);
            ss1 = fmaf(fmaxf(vacc1[k], 0.0f), woutr[k], ss1);
        }
        ss0 += __shfl_xor(ss0, 32, 64);
        ss1 += __shfl_xor(ss1, 32, 64);
        float o0 = fmaxf(ss0 + boutv, 0.0f);
        float o1 = fmaxf(ss1 + boutv, 0.0f);
        o0 += __shfl_xor(o0, 1, 64);  o1 += __shfl_xor(o1, 1, 64);
        o0 += __shfl_xor(o0, 2, 64);  o1 += __shfl_xor(o1, 2, 64);
        o0 += __shfl_xor(o0, 4, 64);  o1 += __shfl_xor(o1, 4, 64);
        if (q == 0 && n8 == 0) {
            long long gg0 = gbase + g0;
            if (gg0 < (long long)B) out[gg0] = o0 * 0.125f;
            long long gg1 = gbase + g1;
            if (gg1 < (long long)B) out[gg1] = o1 * 0.125f;
        }
        buf ^= 1;
    }
}

extern "C" void kernel_launch(void* const* d_in, const int* in_sizes, int n_in,
                              void* d_out, int out_size, void* d_ws, size_t ws_size,
                              hipStream_t stream) {
    const float* x    = (const float*)d_in[0];
    const int*   ei   = (const int*)d_in[1];
    const float* W1   = (const float*)d_in[2];
    const float* b1   = (const float*)d_in[3];
    const float* W2   = (const float*)d_in[4];
    const float* b2   = (const float*)d_in[5];
    const float* Wout = (const float*)d_in[6];
    const float* bout = (const float*)d_in[7];
    float* out = (float*)d_out;
    (void)d_ws; (void)ws_size; (void)out_size; (void)n_in;

    const int B = in_sizes[0] / 24;                 // 262144
    const int ntiles = (B + GPT - 1) / GPT;         // 8192
    const int grid = ntiles < 2048 ? ntiles : 2048; // grid-stride, 4 iters/block
    gnn_kernel<<<grid, 256, 0, stream>>>(x, ei, W1, b1, W2, b2, Wout, bout, out, B, ntiles);
}

// Round 24
// 42.834 us; speedup vs baseline: 1.3517x; 1.3517x over previous
//
#include <hip/hip_runtime.h>

// VanillaGNN via MFMA: B=262144 graphs, N=8 nodes, DIN=3, DH=32, DOUT=1.
// REVERT to r20/21 structure (32.3us; r23's MFMA-L0 was allocator-hostile,
// +8KB LDS spill) + extend the one working lever: ILP-3 (GPT=48, three
// independent 4-graph pipelines per wave, all MFMAs 3-way interleaved).
// Total VALU/wave unchanged (1.5x work, 1/1.5 tiles); gain = latency overlap.
// Staging: 288 float4 per tile -> all 256 threads + tid<32 double-duty
// (second prefetch reg). Tail tile (16 graphs): clamped loads + guarded
// stores; per-graph math is blockdiag-contained.
// CANARIES: absmax exactly 1.2207e-4; LDS ~14464 static (>=22K = spill ->
// revert to r21 and declare); FETCH ~12.3MB.
// Per pipeline: y = A@x (24 fma) -> L1: 2 kappa-packed MFMA (b1 slot 3,
// C=zerov) -> relu/cvt -> GEMM1: 2 MFMA (C=zerov) -> cvt -> AGG: 2 MFMA
// (C=b2rv) -> Wout reduce + shfl tree.
// Verified layouts (gfx950 mfma_f32_32x32x16_bf16, rounds 3-21):
//   A: lane row=l&31, k=8*(l>>5)+j   B: col=l&31, same k
//   C/D: col=l&31, row=(reg&3)+8*(reg>>2)+4*(l>>5)
// pi(kk) = (kk&3)+8*(kk>>2)+4q.
// Precision ledger (measured-free): tlo, w2lo, a32lo, plo.
// Occupancy verdict (r13-r19): pinned at 2 waves/SIMD; registers are free
// within the 256 envelope — but the allocator spills unpredictably (r23),
// hence the LDS canary.

typedef __bf16 bf16x8 __attribute__((ext_vector_type(8)));
typedef float  f32x16 __attribute__((ext_vector_type(16)));

#define GPT 48  // graphs per block tile (4 waves x 3 pipelines x 4 graphs)

__global__ __launch_bounds__(256, 2) void gnn_kernel(
    const float* __restrict__ x,       // [B,8,3]
    const int* __restrict__ ei,        // [2,32] int32
    const float* __restrict__ W1,      // [3,32]
    const float* __restrict__ b1,      // [32]
    const float* __restrict__ W2,      // [32,32]
    const float* __restrict__ b2,      // [32]
    const float* __restrict__ Wout,    // [32]
    const float* __restrict__ bout,    // [1]
    float* __restrict__ out,           // [B]
    int B, int ntiles)
{
    __shared__ float As[64];           // A[n][m] (n=dst)
    __shared__ float degs[8], dinvs[8];
    __shared__ float W1s[96], b1s[32], W2s[1024], b2s[32], Wouts[32];
    __shared__ float xs[2][GPT * 24];  // double-buffered [g][8][3], 2x1152 floats

    const int tid = threadIdx.x;

    // ---- stage weights / build A (once per block) ----
    if (tid < 96) W1s[tid] = W1[tid];
    if (tid < 64) As[tid] = 0.0f;
    if (tid < 32) { b1s[tid] = b1[tid]; b2s[tid] = b2[tid]; Wouts[tid] = Wout[tid]; }
    if (tid < 8)  degs[tid] = 1.0f;
    for (int i = tid; i < 1024; i += 256) W2s[i] = W2[i];
    __syncthreads();
    if (tid < 32) { int d = ei[32 + tid]; atomicAdd(&degs[d], 1.0f); }
    __syncthreads();
    if (tid < 8) dinvs[tid] = 1.0f / sqrtf(degs[tid]);
    __syncthreads();
    if (tid < 32) {
        int s = ei[tid], d = ei[32 + tid];
        atomicAdd(&As[d * 8 + s], dinvs[s] * dinvs[d]);
    } else if (tid < 40) {
        int n = tid - 32;
        atomicAdd(&As[n * 8 + n], dinvs[n] * dinvs[n]);
    }
    __syncthreads();

    // ---- per-lane constants ----
    const int lane = tid & 63;
    const int wv   = tid >> 6;    // wave 0..3
    const int r    = lane & 31;
    const int q    = lane >> 5;   // k-half selector
    const int n8   = r & 7;       // node within graph
    const int gl   = r >> 3;      // graph within pipeline
    const int g0   = wv * 4 + gl;        // pipeline-0 graph
    const int g1   = 16 + wv * 4 + gl;   // pipeline-1 graph
    const int g2   = 32 + wv * 4 + gl;   // pipeline-2 graph

    float arow[8];
    #pragma unroll
    for (int m = 0; m < 8; m++) arow[m] = As[n8 * 8 + m];

    // W1^T A-frags, kappa-packed: slots 0-2 = W1[j][r] (hi s0 / lo s1),
    // slot 3 = b1[r] (paired with B slot3 = q?0:1)
    bf16x8 w1Ahi, w1Alo;
    #pragma unroll
    for (int j = 0; j < 8; j++) { w1Ahi[j] = (__bf16)0.0f; w1Alo[j] = (__bf16)0.0f; }
    #pragma unroll
    for (int j = 0; j < 3; j++) {
        float v = W1s[j * 32 + r];
        __bf16 h = (__bf16)v;
        w1Ahi[j] = h; w1Alo[j] = (__bf16)(v - (float)h);
    }
    {
        float v = b1s[r];
        __bf16 h = (__bf16)v;
        w1Ahi[3] = h; w1Alo[3] = (__bf16)(v - (float)h);
    }

    // W2 B-frags in pi-order (hi only)
    bf16x8 w2hi[2];
    #pragma unroll
    for (int s = 0; s < 2; s++) {
        #pragma unroll
        for (int j = 0; j < 8; j++) {
            int kk = 8 * s + j;
            int hid = (kk & 3) + 8 * (kk >> 2) + 4 * q;
            w2hi[s][j] = (__bf16)W2s[hid * 32 + r];
        }
    }
    // A32T B-frags in pi-order (hi only)
    bf16x8 a32hi[2];
    #pragma unroll
    for (int s = 0; s < 2; s++) {
        #pragma unroll
        for (int j = 0; j < 8; j++) {
            int kk = 8 * s + j;
            float v = ((kk >> 2) == gl) ? arow[(kk & 3) + 4 * q] : 0.0f;
            a32hi[s][j] = (__bf16)v;
        }
    }
    // persistent C-operand vectors + epilogue wout
    f32x16 zerov, b2rv;
    float woutr[16];
    #pragma unroll
    for (int k = 0; k < 16; k++) {
        int hk = (k & 3) + 8 * (k >> 2) + 4 * q;
        zerov[k] = 0.0f;
        b2rv[k] = b2s[hk];
        woutr[k] = Wouts[hk];
    }
    const float boutv = bout[0];

    // ---- x prefetch (tile 0): 288 float4/tile -> tid + (tid<32 second) ----
    const float4* x4 = reinterpret_cast<const float4*>(x);
    const long long nx4 = (long long)B * 6;
    float4 nxA, nxB;
    if (blockIdx.x < ntiles) {
        long long iA = (long long)blockIdx.x * 288 + tid;
        nxA = x4[iA < nx4 ? iA : nx4 - 1];
        if (tid < 32) {
            long long iB = iA + 256;
            nxB = x4[iB < nx4 ? iB : nx4 - 1];
        }
    }
    int buf = 0;

    // ---- tile loop: 1 barrier per 3 pipelines; prefetch after barrier ----
    for (int tile = blockIdx.x; tile < ntiles; tile += gridDim.x) {
        const long long gbase = (long long)tile * GPT;
        *reinterpret_cast<float4*>(&xs[buf][tid * 4]) = nxA;
        if (tid < 32) *reinterpret_cast<float4*>(&xs[buf][(256 + tid) * 4]) = nxB;
        __syncthreads();
        int tnext = tile + gridDim.x;
        if (tnext < ntiles) {
            long long iA = (long long)tnext * 288 + tid;
            nxA = x4[iA < nx4 ? iA : nx4 - 1];
            if (tid < 32) {
                long long iB = iA + 256;
                nxB = x4[iB < nx4 ? iB : nx4 - 1];
            }
        }

        // ---- y = A@x for all three pipelines ----
        float y00 = 0.f, y01 = 0.f, y02 = 0.f;
        float y10 = 0.f, y11 = 0.f, y12 = 0.f;
        float y20 = 0.f, y21 = 0.f, y22 = 0.f;
        {
            float xv[24];
            #pragma unroll
            for (int i = 0; i < 6; i++) {
                float4 v = *reinterpret_cast<float4*>(&xs[buf][g0 * 24 + i * 4]);
                xv[4 * i] = v.x; xv[4 * i + 1] = v.y; xv[4 * i + 2] = v.z; xv[4 * i + 3] = v.w;
            }
            #pragma unroll
            for (int m = 0; m < 8; m++) {
                y00 = fmaf(arow[m], xv[m * 3 + 0], y00);
                y01 = fmaf(arow[m], xv[m * 3 + 1], y01);
                y02 = fmaf(arow[m], xv[m * 3 + 2], y02);
            }
        }
        {
            float xv[24];
            #pragma unroll
            for (int i = 0; i < 6; i++) {
                float4 v = *reinterpret_cast<float4*>(&xs[buf][g1 * 24 + i * 4]);
                xv[4 * i] = v.x; xv[4 * i + 1] = v.y; xv[4 * i + 2] = v.z; xv[4 * i + 3] = v.w;
            }
            #pragma unroll
            for (int m = 0; m < 8; m++) {
                y10 = fmaf(arow[m], xv[m * 3 + 0], y10);
                y11 = fmaf(arow[m], xv[m * 3 + 1], y11);
                y12 = fmaf(arow[m], xv[m * 3 + 2], y12);
            }
        }
        {
            float xv[24];
            #pragma unroll
            for (int i = 0; i < 6; i++) {
                float4 v = *reinterpret_cast<float4*>(&xs[buf][g2 * 24 + i * 4]);
                xv[4 * i] = v.x; xv[4 * i + 1] = v.y; xv[4 * i + 2] = v.z; xv[4 * i + 3] = v.w;
            }
            #pragma unroll
            for (int m = 0; m < 8; m++) {
                y20 = fmaf(arow[m], xv[m * 3 + 0], y20);
                y21 = fmaf(arow[m], xv[m * 3 + 1], y21);
                y22 = fmaf(arow[m], xv[m * 3 + 2], y22);
            }
        }

        // ---- yB for all three pipelines ----
        bf16x8 yB0, yB1, yB2;
        #pragma unroll
        for (int j = 0; j < 8; j++) {
            yB0[j] = (__bf16)0.0f; yB1[j] = (__bf16)0.0f; yB2[j] = (__bf16)0.0f;
        }
        {
            __bf16 a0 = (__bf16)y00, a1 = (__bf16)y01, a2 = (__bf16)y02;
            yB0[0] = q ? (__bf16)(y00 - (float)a0) : a0;
            yB0[1] = q ? (__bf16)(y01 - (float)a1) : a1;
            yB0[2] = q ? (__bf16)(y02 - (float)a2) : a2;
            yB0[3] = q ? (__bf16)0.0f : (__bf16)1.0f;
            __bf16 b0 = (__bf16)y10, b1v = (__bf16)y11, b2v = (__bf16)y12;
            yB1[0] = q ? (__bf16)(y10 - (float)b0) : b0;
            yB1[1] = q ? (__bf16)(y11 - (float)b1v) : b1v;
            yB1[2] = q ? (__bf16)(y12 - (float)b2v) : b2v;
            yB1[3] = q ? (__bf16)0.0f : (__bf16)1.0f;
            __bf16 c0 = (__bf16)y20, c1 = (__bf16)y21, c2 = (__bf16)y22;
            yB2[0] = q ? (__bf16)(y20 - (float)c0) : c0;
            yB2[1] = q ? (__bf16)(y21 - (float)c1) : c1;
            yB2[2] = q ? (__bf16)(y22 - (float)c2) : c2;
            yB2[3] = q ? (__bf16)0.0f : (__bf16)1.0f;
        }

        // ---- L1 MFMAs, 3-way interleaved; C = zerov ----
        f32x16 vacc0, vacc1, vacc2;
        vacc0 = __builtin_amdgcn_mfma_f32_32x32x16_bf16(w1Ahi, yB0, zerov, 0, 0, 0);
        vacc1 = __builtin_amdgcn_mfma_f32_32x32x16_bf16(w1Ahi, yB1, zerov, 0, 0, 0);
        vacc2 = __builtin_amdgcn_mfma_f32_32x32x16_bf16(w1Ahi, yB2, zerov, 0, 0, 0);
        vacc0 = __builtin_amdgcn_mfma_f32_32x32x16_bf16(w1Alo, yB0, vacc0, 0, 0, 0);
        vacc1 = __builtin_amdgcn_mfma_f32_32x32x16_bf16(w1Alo, yB1, vacc1, 0, 0, 0);
        vacc2 = __builtin_amdgcn_mfma_f32_32x32x16_bf16(w1Alo, yB2, vacc2, 0, 0, 0);

        // ---- relu -> h1, hi-only A-frags ----
        bf16x8 phi0[2], phi1[2], phi2[2];
        #pragma unroll
        for (int s = 0; s < 2; s++) {
            #pragma unroll
            for (int j = 0; j < 8; j++) {
                phi0[s][j] = (__bf16)fmaxf(vacc0[8 * s + j], 0.0f);
                phi1[s][j] = (__bf16)fmaxf(vacc1[8 * s + j], 0.0f);
                phi2[s][j] = (__bf16)fmaxf(vacc2[8 * s + j], 0.0f);
            }
        }

        // ---- GEMM1 MFMAs, 3-way interleaved; C = zerov ----
        vacc0 = __builtin_amdgcn_mfma_f32_32x32x16_bf16(phi0[0], w2hi[0], zerov, 0, 0, 0);
        vacc1 = __builtin_amdgcn_mfma_f32_32x32x16_bf16(phi1[0], w2hi[0], zerov, 0, 0, 0);
        vacc2 = __builtin_amdgcn_mfma_f32_32x32x16_bf16(phi2[0], w2hi[0], zerov, 0, 0, 0);
        vacc0 = __builtin_amdgcn_mfma_f32_32x32x16_bf16(phi0[1], w2hi[1], vacc0, 0, 0, 0);
        vacc1 = __builtin_amdgcn_mfma_f32_32x32x16_bf16(phi1[1], w2hi[1], vacc1, 0, 0, 0);
        vacc2 = __builtin_amdgcn_mfma_f32_32x32x16_bf16(phi2[1], w2hi[1], vacc2, 0, 0, 0);

        // ---- t^T A-frags: hi-only DIRECT conversion ----
        bf16x8 thi0[2], thi1[2], thi2[2];
        #pragma unroll
        for (int s = 0; s < 2; s++) {
            #pragma unroll
            for (int j = 0; j < 8; j++) {
                thi0[s][j] = (__bf16)vacc0[8 * s + j];
                thi1[s][j] = (__bf16)vacc1[8 * s + j];
                thi2[s][j] = (__bf16)vacc2[8 * s + j];
            }
        }

        // ---- AGG MFMAs, 3-way interleaved; C = b2rv ----
        vacc0 = __builtin_amdgcn_mfma_f32_32x32x16_bf16(thi0[0], a32hi[0], b2rv, 0, 0, 0);
        vacc1 = __builtin_amdgcn_mfma_f32_32x32x16_bf16(thi1[0], a32hi[0], b2rv, 0, 0, 0);
        vacc2 = __builtin_amdgcn_mfma_f32_32x32x16_bf16(thi2[0], a32hi[0], b2rv, 0, 0, 0);
        vacc0 = __builtin_amdgcn_mfma_f32_32x32x16_bf16(thi0[1], a32hi[1], vacc0, 0, 0, 0);
        vacc1 = __builtin_amdgcn_mfma_f32_32x32x16_bf16(thi1[1], a32hi[1], vacc1, 0, 0, 0);
        vacc2 = __builtin_amdgcn_mfma_f32_32x32x16_bf16(thi2[1], a32hi[1], vacc2, 0, 0, 0);

        // ---- epilogues, interleaved (independent shfl chains) ----
        float ss0 = 0.0f, ss1 = 0.0f, ss2 = 0.0f;
        #pragma unroll
        for (int k = 0; k < 16; k++) {
            ss0 = fmaf(fmaxf(vacc0[k], 0.0f), woutr[k], ss0);
            ss1 = fmaf(fmaxf(vacc1[k], 0.0f), woutr[k], ss1);
            ss2 = fmaf(fmaxf(vacc2[k], 0.0f), woutr[k], ss2);
        }
        ss0 += __shfl_xor(ss0, 32, 64);
        ss1 += __shfl_xor(ss1, 32, 64);
        ss2 += __shfl_xor(ss2, 32, 64);
        float o0 = fmaxf(ss0 + boutv, 0.0f);
        float o1 = fmaxf(ss1 + boutv, 0.0f);
        float o2 = fmaxf(ss2 + boutv, 0.0f);
        o0 += __shfl_xor(o0, 1, 64); o1 += __shfl_xor(o1, 1, 64); o2 += __shfl_xor(o2, 1, 64);
        o0 += __shfl_xor(o0, 2, 64); o1 += __shfl_xor(o1, 2, 64); o2 += __shfl_xor(o2, 2, 64);
        o0 += __shfl_xor(o0, 4, 64); o1 += __shfl_xor(o1, 4, 64); o2 += __shfl_xor(o2, 4, 64);
        if (q == 0 && n8 == 0) {
            long long gg0 = gbase + g0;
            if (gg0 < (long long)B) out[gg0] = o0 * 0.125f;
            long long gg1 = gbase + g1;
            if (gg1 < (long long)B) out[gg1] = o1 * 0.125f;
            long long gg2 = gbase + g2;
            if (gg2 < (long long)B) out[gg2] = o2 * 0.125f;
        }
        buf ^= 1;
    }
}

extern "C" void kernel_launch(void* const* d_in, const int* in_sizes, int n_in,
                              void* d_out, int out_size, void* d_ws, size_t ws_size,
                              hipStream_t stream) {
    const float* x    = (const float*)d_in[0];
    const int*   ei   = (const int*)d_in[1];
    const float* W1   = (const float*)d_in[2];
    const float* b1   = (const float*)d_in[3];
    const float* W2   = (const float*)d_in[4];
    const float* b2   = (const float*)d_in[5];
    const float* Wout = (const float*)d_in[6];
    const float* bout = (const float*)d_in[7];
    float* out = (float*)d_out;
    (void)d_ws; (void)ws_size; (void)out_size; (void)n_in;

    const int B = in_sizes[0] / 24;                 // 262144
    const int ntiles = (B + GPT - 1) / GPT;         // 5462 (last tile partial)
    const int grid = ntiles < 2048 ? ntiles : 2048; // grid-stride
    gnn_kernel<<<grid, 256, 0, stream>>>(x, ei, W1, b1, W2, b2, Wout, bout, out, B, ntiles);
}

// Round 25
// 31.527 us; speedup vs baseline: 1.8365x; 1.3586x over previous
//
#include <hip/hip_runtime.h>

// VanillaGNN via MFMA: B=262144 graphs, N=8 nodes, DIN=3, DH=32, DOUT=1.
// r21 structure (32.3us best; ILP-3 r24 regressed -> reverted) + ONE change:
// BARRIER-FREE main loop. B = 2048 blocks x 4 tiles x 32 graphs exactly, and
// 4 tiles of x = 12KB fits LDS -> stage ALL 4 tiles up front (3 coalesced
// float4/thread), ONE barrier, then an unrolled 4-iter compute loop with NO
// barriers: scheduler gains cross-tile overlap (epilogue_i || y-stage_{i+1}),
// and the per-tile vmcnt/lgkm barrier drain disappears. Also deletes the
// prefetch/double-buffer machinery (-8 VGPR).
// CANARIES: absmax exactly 1.2207e-4; LDS ~17.7KB static (>=25KB = spill ->
// revert to r21 and declare); FETCH ~12.3MB; WRITE ~1MB.
// Per pipeline (2 per wave, ILP2): y = A@x (24 fma) -> L1: 2 kappa-packed
// MFMA (b1 slot 3, C=zerov) -> relu/cvt -> GEMM1: 2 MFMA (C=zerov) -> cvt ->
// AGG: 2 MFMA (C=b2rv) -> Wout reduce + shfl tree. MFMAs p0/p1 interleaved.
// Verified layouts (gfx950 mfma_f32_32x32x16_bf16, rounds 3-21):
//   A: lane row=l&31, k=8*(l>>5)+j   B: col=l&31, same k
//   C/D: col=l&31, row=(reg&3)+8*(reg>>2)+4*(l>>5)
// pi(kk) = (kk&3)+8*(kk>>2)+4q.
// Precision ledger (measured-free): tlo, w2lo, a32lo, plo.
// Occupancy verdict (r13-r19): pinned at 2 waves/SIMD; ILP saturates at 2
// (r24); launch_bounds >=4 spills (r17/r18). This is the latency-overlap
// lever that remains.

typedef __bf16 bf16x8 __attribute__((ext_vector_type(8)));
typedef float  f32x16 __attribute__((ext_vector_type(16)));

#define GPT 32  // graphs per tile (4 waves x 2 pipelines x 4 graphs)
#define TPB 4   // tiles per block (B = 2048 * TPB * GPT exactly)

__global__ __launch_bounds__(256, 2) void gnn_kernel(
    const float* __restrict__ x,       // [B,8,3]
    const int* __restrict__ ei,        // [2,32] int32
    const float* __restrict__ W1,      // [3,32]
    const float* __restrict__ b1,      // [32]
    const float* __restrict__ W2,      // [32,32]
    const float* __restrict__ b2,      // [32]
    const float* __restrict__ Wout,    // [32]
    const float* __restrict__ bout,    // [1]
    float* __restrict__ out,           // [B]
    int B)
{
    __shared__ float As[64];           // A[n][m] (n=dst)
    __shared__ float degs[8], dinvs[8];
    __shared__ float W1s[96], b1s[32], W2s[1024], b2s[32], Wouts[32];
    __shared__ float xs[TPB * GPT * 24];  // 4 tiles x [g][8][3] = 12KB

    const int tid = threadIdx.x;

    // ---- stage weights / x (all 4 tiles) / build A — ONE barrier phase ----
    if (tid < 96) W1s[tid] = W1[tid];
    if (tid < 64) As[tid] = 0.0f;
    if (tid < 32) { b1s[tid] = b1[tid]; b2s[tid] = b2[tid]; Wouts[tid] = Wout[tid]; }
    if (tid < 8)  degs[tid] = 1.0f;
    for (int i = tid; i < 1024; i += 256) W2s[i] = W2[i];
    {   // x: 768 float4 per block, contiguous; 3 per thread
        const float4* x4 = reinterpret_cast<const float4*>(x);
        long long base4 = (long long)blockIdx.x * (TPB * GPT * 6);
        float4* xs4 = reinterpret_cast<float4*>(xs);
        #pragma unroll
        for (int i = 0; i < 3; i++)
            xs4[tid + 256 * i] = x4[base4 + tid + 256 * i];
    }
    __syncthreads();
    if (tid < 32) { int d = ei[32 + tid]; atomicAdd(&degs[d], 1.0f); }
    __syncthreads();
    if (tid < 8) dinvs[tid] = 1.0f / sqrtf(degs[tid]);
    __syncthreads();
    if (tid < 32) {
        int s = ei[tid], d = ei[32 + tid];
        atomicAdd(&As[d * 8 + s], dinvs[s] * dinvs[d]);
    } else if (tid < 40) {
        int n = tid - 32;
        atomicAdd(&As[n * 8 + n], dinvs[n] * dinvs[n]);
    }
    __syncthreads();   // last barrier — loop below is barrier-free

    // ---- per-lane constants ----
    const int lane = tid & 63;
    const int wv   = tid >> 6;    // wave 0..3
    const int r    = lane & 31;
    const int q    = lane >> 5;   // k-half selector
    const int n8   = r & 7;       // node within graph
    const int gl   = r >> 3;      // graph within pipeline
    const int g0   = wv * 4 + gl;       // pipeline-0 graph
    const int g1   = 16 + wv * 4 + gl;  // pipeline-1 graph

    float arow[8];
    #pragma unroll
    for (int m = 0; m < 8; m++) arow[m] = As[n8 * 8 + m];

    // W1^T A-frags, kappa-packed: slots 0-2 = W1[j][r] (hi s0 / lo s1),
    // slot 3 = b1[r] (paired with B slot3 = q?0:1)
    bf16x8 w1Ahi, w1Alo;
    #pragma unroll
    for (int j = 0; j < 8; j++) { w1Ahi[j] = (__bf16)0.0f; w1Alo[j] = (__bf16)0.0f; }
    #pragma unroll
    for (int j = 0; j < 3; j++) {
        float v = W1s[j * 32 + r];
        __bf16 h = (__bf16)v;
        w1Ahi[j] = h; w1Alo[j] = (__bf16)(v - (float)h);
    }
    {
        float v = b1s[r];
        __bf16 h = (__bf16)v;
        w1Ahi[3] = h; w1Alo[3] = (__bf16)(v - (float)h);
    }

    // W2 B-frags in pi-order (hi only)
    bf16x8 w2hi[2];
    #pragma unroll
    for (int s = 0; s < 2; s++) {
        #pragma unroll
        for (int j = 0; j < 8; j++) {
            int kk = 8 * s + j;
            int hid = (kk & 3) + 8 * (kk >> 2) + 4 * q;
            w2hi[s][j] = (__bf16)W2s[hid * 32 + r];
        }
    }
    // A32T B-frags in pi-order (hi only)
    bf16x8 a32hi[2];
    #pragma unroll
    for (int s = 0; s < 2; s++) {
        #pragma unroll
        for (int j = 0; j < 8; j++) {
            int kk = 8 * s + j;
            float v = ((kk >> 2) == gl) ? arow[(kk & 3) + 4 * q] : 0.0f;
            a32hi[s][j] = (__bf16)v;
        }
    }
    // persistent C-operand vectors + epilogue wout
    f32x16 zerov, b2rv;
    float woutr[16];
    #pragma unroll
    for (int k = 0; k < 16; k++) {
        int hk = (k & 3) + 8 * (k >> 2) + 4 * q;
        zerov[k] = 0.0f;
        b2rv[k] = b2s[hk];
        woutr[k] = Wouts[hk];
    }
    const float boutv = bout[0];

    // ---- barrier-free compute loop over the 4 pre-staged tiles ----
    #pragma unroll
    for (int it = 0; it < TPB; it++) {
        const long long gbase = ((long long)blockIdx.x * TPB + it) * GPT;
        const float* xt = &xs[it * GPT * 24];

        // ---- y = A@x, both pipelines ----
        float y00 = 0.f, y01 = 0.f, y02 = 0.f;
        {
            float xv[24];
            #pragma unroll
            for (int i = 0; i < 6; i++) {
                float4 v = *reinterpret_cast<const float4*>(&xt[g0 * 24 + i * 4]);
                xv[4 * i] = v.x; xv[4 * i + 1] = v.y; xv[4 * i + 2] = v.z; xv[4 * i + 3] = v.w;
            }
            #pragma unroll
            for (int m = 0; m < 8; m++) {
                y00 = fmaf(arow[m], xv[m * 3 + 0], y00);
                y01 = fmaf(arow[m], xv[m * 3 + 1], y01);
                y02 = fmaf(arow[m], xv[m * 3 + 2], y02);
            }
        }
        float y10 = 0.f, y11 = 0.f, y12 = 0.f;
        {
            float xv[24];
            #pragma unroll
            for (int i = 0; i < 6; i++) {
                float4 v = *reinterpret_cast<const float4*>(&xt[g1 * 24 + i * 4]);
                xv[4 * i] = v.x; xv[4 * i + 1] = v.y; xv[4 * i + 2] = v.z; xv[4 * i + 3] = v.w;
            }
            #pragma unroll
            for (int m = 0; m < 8; m++) {
                y10 = fmaf(arow[m], xv[m * 3 + 0], y10);
                y11 = fmaf(arow[m], xv[m * 3 + 1], y11);
                y12 = fmaf(arow[m], xv[m * 3 + 2], y12);
            }
        }

        // ---- yB for both pipelines ----
        bf16x8 yB0, yB1;
        #pragma unroll
        for (int j = 0; j < 8; j++) { yB0[j] = (__bf16)0.0f; yB1[j] = (__bf16)0.0f; }
        {
            __bf16 h0 = (__bf16)y00, h1 = (__bf16)y01, h2 = (__bf16)y02;
            yB0[0] = q ? (__bf16)(y00 - (float)h0) : h0;
            yB0[1] = q ? (__bf16)(y01 - (float)h1) : h1;
            yB0[2] = q ? (__bf16)(y02 - (float)h2) : h2;
            yB0[3] = q ? (__bf16)0.0f : (__bf16)1.0f;
            __bf16 g0h = (__bf16)y10, g1h = (__bf16)y11, g2h = (__bf16)y12;
            yB1[0] = q ? (__bf16)(y10 - (float)g0h) : g0h;
            yB1[1] = q ? (__bf16)(y11 - (float)g1h) : g1h;
            yB1[2] = q ? (__bf16)(y12 - (float)g2h) : g2h;
            yB1[3] = q ? (__bf16)0.0f : (__bf16)1.0f;
        }

        // ---- L1 MFMAs, interleaved p0/p1; C = zerov ----
        f32x16 vacc0, vacc1;
        vacc0 = __builtin_amdgcn_mfma_f32_32x32x16_bf16(w1Ahi, yB0, zerov, 0, 0, 0);
        vacc1 = __builtin_amdgcn_mfma_f32_32x32x16_bf16(w1Ahi, yB1, zerov, 0, 0, 0);
        vacc0 = __builtin_amdgcn_mfma_f32_32x32x16_bf16(w1Alo, yB0, vacc0, 0, 0, 0);
        vacc1 = __builtin_amdgcn_mfma_f32_32x32x16_bf16(w1Alo, yB1, vacc1, 0, 0, 0);

        // ---- relu -> h1, hi-only A-frags ----
        bf16x8 phi0[2], phi1[2];
        #pragma unroll
        for (int s = 0; s < 2; s++) {
            #pragma unroll
            for (int j = 0; j < 8; j++) {
                phi0[s][j] = (__bf16)fmaxf(vacc0[8 * s + j], 0.0f);
                phi1[s][j] = (__bf16)fmaxf(vacc1[8 * s + j], 0.0f);
            }
        }

        // ---- GEMM1 MFMAs, interleaved; C = zerov ----
        vacc0 = __builtin_amdgcn_mfma_f32_32x32x16_bf16(phi0[0], w2hi[0], zerov, 0, 0, 0);
        vacc1 = __builtin_amdgcn_mfma_f32_32x32x16_bf16(phi1[0], w2hi[0], zerov, 0, 0, 0);
        vacc0 = __builtin_amdgcn_mfma_f32_32x32x16_bf16(phi0[1], w2hi[1], vacc0, 0, 0, 0);
        vacc1 = __builtin_amdgcn_mfma_f32_32x32x16_bf16(phi1[1], w2hi[1], vacc1, 0, 0, 0);

        // ---- t^T A-frags: hi-only DIRECT conversion ----
        bf16x8 thi0[2], thi1[2];
        #pragma unroll
        for (int s = 0; s < 2; s++) {
            #pragma unroll
            for (int j = 0; j < 8; j++) {
                thi0[s][j] = (__bf16)vacc0[8 * s + j];
                thi1[s][j] = (__bf16)vacc1[8 * s + j];
            }
        }

        // ---- AGG MFMAs, interleaved; C = b2rv ----
        vacc0 = __builtin_amdgcn_mfma_f32_32x32x16_bf16(thi0[0], a32hi[0], b2rv, 0, 0, 0);
        vacc1 = __builtin_amdgcn_mfma_f32_32x32x16_bf16(thi1[0], a32hi[0], b2rv, 0, 0, 0);
        vacc0 = __builtin_amdgcn_mfma_f32_32x32x16_bf16(thi0[1], a32hi[1], vacc0, 0, 0, 0);
        vacc1 = __builtin_amdgcn_mfma_f32_32x32x16_bf16(thi1[1], a32hi[1], vacc1, 0, 0, 0);

        // ---- epilogues, interleaved (independent shfl chains) ----
        float ss0 = 0.0f, ss1 = 0.0f;
        #pragma unroll
        for (int k = 0; k < 16; k++) {
            ss0 = fmaf(fmaxf(vacc0[k], 0.0f), woutr[k], ss0);
            ss1 = fmaf(fmaxf(vacc1[k], 0.0f), woutr[k], ss1);
        }
        ss0 += __shfl_xor(ss0, 32, 64);
        ss1 += __shfl_xor(ss1, 32, 64);
        float o0 = fmaxf(ss0 + boutv, 0.0f);
        float o1 = fmaxf(ss1 + boutv, 0.0f);
        o0 += __shfl_xor(o0, 1, 64);  o1 += __shfl_xor(o1, 1, 64);
        o0 += __shfl_xor(o0, 2, 64);  o1 += __shfl_xor(o1, 2, 64);
        o0 += __shfl_xor(o0, 4, 64);  o1 += __shfl_xor(o1, 4, 64);
        if (q == 0 && n8 == 0) {
            long long gg0 = gbase + g0;
            if (gg0 < (long long)B) out[gg0] = o0 * 0.125f;
            long long gg1 = gbase + g1;
            if (gg1 < (long long)B) out[gg1] = o1 * 0.125f;
        }
    }
}

extern "C" void kernel_launch(void* const* d_in, const int* in_sizes, int n_in,
                              void* d_out, int out_size, void* d_ws, size_t ws_size,
                              hipStream_t stream) {
    const float* x    = (const float*)d_in[0];
    const int*   ei   = (const int*)d_in[1];
    const float* W1   = (const float*)d_in[2];
    const float* b1   = (const float*)d_in[3];
    const float* W2   = (const float*)d_in[4];
    const float* b2   = (const float*)d_in[5];
    const float* Wout = (const float*)d_in[6];
    const float* bout = (const float*)d_in[7];
    float* out = (float*)d_out;
    (void)d_ws; (void)ws_size; (void)out_size; (void)n_in;

    const int B = in_sizes[0] / 24;            // 262144 = 2048 * TPB * GPT exactly
    const int grid = B / (TPB * GPT);          // 2048 blocks, 4 tiles each
    gnn_kernel<<<grid, 256, 0, stream>>>(x, ei, W1, b1, W2, b2, Wout, bout, out, B);
}

// Round 26
// 30.635 us; speedup vs baseline: 1.8899x; 1.0291x over previous
//
#include <hip/hip_runtime.h>

// VanillaGNN via MFMA: B=262144 graphs, N=8 nodes, DIN=3, DH=32, DOUT=1.
// r25 structure (31.5us best) + ONE change: TPB 4->8, grid 2048->1024.
// Per-CU accounting: prologue (~800cy: weights+A-build+frags) was paid by
// 8 sequential blocks/CU (~8% of wall); TPB=8 halves that to 4, and the
// barrier-free unrolled stream doubles for cross-tile overlap.
// B = 1024 x 8 x 32 exactly. LDS 24KB(x) + 5.2KB = ~29.4KB static -> still
// 2 blocks/CU (58.8 < 160KB), occupancy unchanged.
// CANARIES: absmax exactly 1.2207e-4; LDS ~29440 (>=37K = spill -> revert
// to r25 and declare); FETCH ~12.3MB; WRITE ~1MB.
// Per pipeline (2 per wave, ILP2): y = A@x (24 fma) -> L1: 2 kappa-packed
// MFMA (b1 slot 3, C=zerov) -> relu/cvt -> GEMM1: 2 MFMA (C=zerov) -> cvt ->
// AGG: 2 MFMA (C=b2rv) -> Wout reduce + shfl tree. MFMAs p0/p1 interleaved.
// Verified layouts (gfx950 mfma_f32_32x32x16_bf16, rounds 3-21):
//   A: lane row=l&31, k=8*(l>>5)+j   B: col=l&31, same k
//   C/D: col=l&31, row=(reg&3)+8*(reg>>2)+4*(l>>5)
// pi(kk) = (kk&3)+8*(kk>>2)+4q.
// Precision ledger (measured-free): tlo, w2lo, a32lo, plo.
// Falsified levers: occupancy (r13-19), forced envelope (r17/18 spill),
// ILP>=3 (r24), MFMA-L0 (r23 spill), C-op init (r21 null).

typedef __bf16 bf16x8 __attribute__((ext_vector_type(8)));
typedef float  f32x16 __attribute__((ext_vector_type(16)));

#define GPT 32  // graphs per tile (4 waves x 2 pipelines x 4 graphs)
#define TPB 8   // tiles per block (B = 1024 * TPB * GPT exactly)

__global__ __launch_bounds__(256, 2) void gnn_kernel(
    const float* __restrict__ x,       // [B,8,3]
    const int* __restrict__ ei,        // [2,32] int32
    const float* __restrict__ W1,      // [3,32]
    const float* __restrict__ b1,      // [32]
    const float* __restrict__ W2,      // [32,32]
    const float* __restrict__ b2,      // [32]
    const float* __restrict__ Wout,    // [32]
    const float* __restrict__ bout,    // [1]
    float* __restrict__ out,           // [B]
    int B)
{
    __shared__ float As[64];           // A[n][m] (n=dst)
    __shared__ float degs[8], dinvs[8];
    __shared__ float W1s[96], b1s[32], W2s[1024], b2s[32], Wouts[32];
    __shared__ float xs[TPB * GPT * 24];  // 8 tiles x [g][8][3] = 24KB

    const int tid = threadIdx.x;

    // ---- stage weights / x (all 8 tiles) / build A — prologue ----
    if (tid < 96) W1s[tid] = W1[tid];
    if (tid < 64) As[tid] = 0.0f;
    if (tid < 32) { b1s[tid] = b1[tid]; b2s[tid] = b2[tid]; Wouts[tid] = Wout[tid]; }
    if (tid < 8)  degs[tid] = 1.0f;
    for (int i = tid; i < 1024; i += 256) W2s[i] = W2[i];
    {   // x: 1536 float4 per block, contiguous; 6 per thread
        const float4* x4 = reinterpret_cast<const float4*>(x);
        long long base4 = (long long)blockIdx.x * (TPB * GPT * 6);
        float4* xs4 = reinterpret_cast<float4*>(xs);
        #pragma unroll
        for (int i = 0; i < 6; i++)
            xs4[tid + 256 * i] = x4[base4 + tid + 256 * i];
    }
    __syncthreads();
    if (tid < 32) { int d = ei[32 + tid]; atomicAdd(&degs[d], 1.0f); }
    __syncthreads();
    if (tid < 8) dinvs[tid] = 1.0f / sqrtf(degs[tid]);
    __syncthreads();
    if (tid < 32) {
        int s = ei[tid], d = ei[32 + tid];
        atomicAdd(&As[d * 8 + s], dinvs[s] * dinvs[d]);
    } else if (tid < 40) {
        int n = tid - 32;
        atomicAdd(&As[n * 8 + n], dinvs[n] * dinvs[n]);
    }
    __syncthreads();   // last barrier — loop below is barrier-free

    // ---- per-lane constants ----
    const int lane = tid & 63;
    const int wv   = tid >> 6;    // wave 0..3
    const int r    = lane & 31;
    const int q    = lane >> 5;   // k-half selector
    const int n8   = r & 7;       // node within graph
    const int gl   = r >> 3;      // graph within pipeline
    const int g0   = wv * 4 + gl;       // pipeline-0 graph
    const int g1   = 16 + wv * 4 + gl;  // pipeline-1 graph

    float arow[8];
    #pragma unroll
    for (int m = 0; m < 8; m++) arow[m] = As[n8 * 8 + m];

    // W1^T A-frags, kappa-packed: slots 0-2 = W1[j][r] (hi s0 / lo s1),
    // slot 3 = b1[r] (paired with B slot3 = q?0:1)
    bf16x8 w1Ahi, w1Alo;
    #pragma unroll
    for (int j = 0; j < 8; j++) { w1Ahi[j] = (__bf16)0.0f; w1Alo[j] = (__bf16)0.0f; }
    #pragma unroll
    for (int j = 0; j < 3; j++) {
        float v = W1s[j * 32 + r];
        __bf16 h = (__bf16)v;
        w1Ahi[j] = h; w1Alo[j] = (__bf16)(v - (float)h);
    }
    {
        float v = b1s[r];
        __bf16 h = (__bf16)v;
        w1Ahi[3] = h; w1Alo[3] = (__bf16)(v - (float)h);
    }

    // W2 B-frags in pi-order (hi only)
    bf16x8 w2hi[2];
    #pragma unroll
    for (int s = 0; s < 2; s++) {
        #pragma unroll
        for (int j = 0; j < 8; j++) {
            int kk = 8 * s + j;
            int hid = (kk & 3) + 8 * (kk >> 2) + 4 * q;
            w2hi[s][j] = (__bf16)W2s[hid * 32 + r];
        }
    }
    // A32T B-frags in pi-order (hi only)
    bf16x8 a32hi[2];
    #pragma unroll
    for (int s = 0; s < 2; s++) {
        #pragma unroll
        for (int j = 0; j < 8; j++) {
            int kk = 8 * s + j;
            float v = ((kk >> 2) == gl) ? arow[(kk & 3) + 4 * q] : 0.0f;
            a32hi[s][j] = (__bf16)v;
        }
    }
    // persistent C-operand vectors + epilogue wout
    f32x16 zerov, b2rv;
    float woutr[16];
    #pragma unroll
    for (int k = 0; k < 16; k++) {
        int hk = (k & 3) + 8 * (k >> 2) + 4 * q;
        zerov[k] = 0.0f;
        b2rv[k] = b2s[hk];
        woutr[k] = Wouts[hk];
    }
    const float boutv = bout[0];

    // ---- barrier-free compute loop over the 8 pre-staged tiles ----
    #pragma unroll 4
    for (int it = 0; it < TPB; it++) {
        const long long gbase = ((long long)blockIdx.x * TPB + it) * GPT;
        const float* xt = &xs[it * GPT * 24];

        // ---- y = A@x, both pipelines ----
        float y00 = 0.f, y01 = 0.f, y02 = 0.f;
        {
            float xv[24];
            #pragma unroll
            for (int i = 0; i < 6; i++) {
                float4 v = *reinterpret_cast<const float4*>(&xt[g0 * 24 + i * 4]);
                xv[4 * i] = v.x; xv[4 * i + 1] = v.y; xv[4 * i + 2] = v.z; xv[4 * i + 3] = v.w;
            }
            #pragma unroll
            for (int m = 0; m < 8; m++) {
                y00 = fmaf(arow[m], xv[m * 3 + 0], y00);
                y01 = fmaf(arow[m], xv[m * 3 + 1], y01);
                y02 = fmaf(arow[m], xv[m * 3 + 2], y02);
            }
        }
        float y10 = 0.f, y11 = 0.f, y12 = 0.f;
        {
            float xv[24];
            #pragma unroll
            for (int i = 0; i < 6; i++) {
                float4 v = *reinterpret_cast<const float4*>(&xt[g1 * 24 + i * 4]);
                xv[4 * i] = v.x; xv[4 * i + 1] = v.y; xv[4 * i + 2] = v.z; xv[4 * i + 3] = v.w;
            }
            #pragma unroll
            for (int m = 0; m < 8; m++) {
                y10 = fmaf(arow[m], xv[m * 3 + 0], y10);
                y11 = fmaf(arow[m], xv[m * 3 + 1], y11);
                y12 = fmaf(arow[m], xv[m * 3 + 2], y12);
            }
        }

        // ---- yB for both pipelines ----
        bf16x8 yB0, yB1;
        #pragma unroll
        for (int j = 0; j < 8; j++) { yB0[j] = (__bf16)0.0f; yB1[j] = (__bf16)0.0f; }
        {
            __bf16 h0 = (__bf16)y00, h1 = (__bf16)y01, h2 = (__bf16)y02;
            yB0[0] = q ? (__bf16)(y00 - (float)h0) : h0;
            yB0[1] = q ? (__bf16)(y01 - (float)h1) : h1;
            yB0[2] = q ? (__bf16)(y02 - (float)h2) : h2;
            yB0[3] = q ? (__bf16)0.0f : (__bf16)1.0f;
            __bf16 g0h = (__bf16)y10, g1h = (__bf16)y11, g2h = (__bf16)y12;
            yB1[0] = q ? (__bf16)(y10 - (float)g0h) : g0h;
            yB1[1] = q ? (__bf16)(y11 - (float)g1h) : g1h;
            yB1[2] = q ? (__bf16)(y12 - (float)g2h) : g2h;
            yB1[3] = q ? (__bf16)0.0f : (__bf16)1.0f;
        }

        // ---- L1 MFMAs, interleaved p0/p1; C = zerov ----
        f32x16 vacc0, vacc1;
        vacc0 = __builtin_amdgcn_mfma_f32_32x32x16_bf16(w1Ahi, yB0, zerov, 0, 0, 0);
        vacc1 = __builtin_amdgcn_mfma_f32_32x32x16_bf16(w1Ahi, yB1, zerov, 0, 0, 0);
        vacc0 = __builtin_amdgcn_mfma_f32_32x32x16_bf16(w1Alo, yB0, vacc0, 0, 0, 0);
        vacc1 = __builtin_amdgcn_mfma_f32_32x32x16_bf16(w1Alo, yB1, vacc1, 0, 0, 0);

        // ---- relu -> h1, hi-only A-frags ----
        bf16x8 phi0[2], phi1[2];
        #pragma unroll
        for (int s = 0; s < 2; s++) {
            #pragma unroll
            for (int j = 0; j < 8; j++) {
                phi0[s][j] = (__bf16)fmaxf(vacc0[8 * s + j], 0.0f);
                phi1[s][j] = (__bf16)fmaxf(vacc1[8 * s + j], 0.0f);
            }
        }

        // ---- GEMM1 MFMAs, interleaved; C = zerov ----
        vacc0 = __builtin_amdgcn_mfma_f32_32x32x16_bf16(phi0[0], w2hi[0], zerov, 0, 0, 0);
        vacc1 = __builtin_amdgcn_mfma_f32_32x32x16_bf16(phi1[0], w2hi[0], zerov, 0, 0, 0);
        vacc0 = __builtin_amdgcn_mfma_f32_32x32x16_bf16(phi0[1], w2hi[1], vacc0, 0, 0, 0);
        vacc1 = __builtin_amdgcn_mfma_f32_32x32x16_bf16(phi1[1], w2hi[1], vacc1, 0, 0, 0);

        // ---- t^T A-frags: hi-only DIRECT conversion ----
        bf16x8 thi0[2], thi1[2];
        #pragma unroll
        for (int s = 0; s < 2; s++) {
            #pragma unroll
            for (int j = 0; j < 8; j++) {
                thi0[s][j] = (__bf16)vacc0[8 * s + j];
                thi1[s][j] = (__bf16)vacc1[8 * s + j];
            }
        }

        // ---- AGG MFMAs, interleaved; C = b2rv ----
        vacc0 = __builtin_amdgcn_mfma_f32_32x32x16_bf16(thi0[0], a32hi[0], b2rv, 0, 0, 0);
        vacc1 = __builtin_amdgcn_mfma_f32_32x32x16_bf16(thi1[0], a32hi[0], b2rv, 0, 0, 0);
        vacc0 = __builtin_amdgcn_mfma_f32_32x32x16_bf16(thi0[1], a32hi[1], vacc0, 0, 0, 0);
        vacc1 = __builtin_amdgcn_mfma_f32_32x32x16_bf16(thi1[1], a32hi[1], vacc1, 0, 0, 0);

        // ---- epilogues, interleaved (independent shfl chains) ----
        float ss0 = 0.0f, ss1 = 0.0f;
        #pragma unroll
        for (int k = 0; k < 16; k++) {
            ss0 = fmaf(fmaxf(vacc0[k], 0.0f), woutr[k], ss0);
            ss1 = fmaf(fmaxf(vacc1[k], 0.0f), woutr[k], ss1);
        }
        ss0 += __shfl_xor(ss0, 32, 64);
        ss1 += __shfl_xor(ss1, 32, 64);
        float o0 = fmaxf(ss0 + boutv, 0.0f);
        float o1 = fmaxf(ss1 + boutv, 0.0f);
        o0 += __shfl_xor(o0, 1, 64);  o1 += __shfl_xor(o1, 1, 64);
        o0 += __shfl_xor(o0, 2, 64);  o1 += __shfl_xor(o1, 2, 64);
        o0 += __shfl_xor(o0, 4, 64);  o1 += __shfl_xor(o1, 4, 64);
        if (q == 0 && n8 == 0) {
            long long gg0 = gbase + g0;
            if (gg0 < (long long)B) out[gg0] = o0 * 0.125f;
            long long gg1 = gbase + g1;
            if (gg1 < (long long)B) out[gg1] = o1 * 0.125f;
        }
    }
}

extern "C" void kernel_launch(void* const* d_in, const int* in_sizes, int n_in,
                              void* d_out, int out_size, void* d_ws, size_t ws_size,
                              hipStream_t stream) {
    const float* x    = (const float*)d_in[0];
    const int*   ei   = (const int*)d_in[1];
    const float* W1   = (const float*)d_in[2];
    const float* b1   = (const float*)d_in[3];
    const float* W2   = (const float*)d_in[4];
    const float* b2   = (const float*)d_in[5];
    const float* Wout = (const float*)d_in[6];
    const float* bout = (const float*)d_in[7];
    float* out = (float*)d_out;
    (void)d_ws; (void)ws_size; (void)out_size; (void)n_in;

    const int B = in_sizes[0] / 24;            // 262144 = 1024 * TPB * GPT exactly
    const int grid = B / (TPB * GPT);          // 1024 blocks, 8 tiles each
    gnn_kernel<<<grid, 256, 0, stream>>>(x, ei, W1, b1, W2, b2, Wout, bout, out, B);
}